// Round 1
// baseline (1090.652 us; speedup 1.0000x reference)
//
#include <hip/hip_runtime.h>

#define N_ROWS 16384
#define N_EMB  8192
#define DIM    512
#define NCAND  16

#define GAS __attribute__((address_space(1)))
#define LAS __attribute__((address_space(3)))

// ---------------------------------------------------------------------------
// ws layout:
//   [0]    double lossAcc (16 B, zeroed)
//   [16]   int cand[N_ROWS * NCAND]   (1 MB)
// k_hot region (512 MB at d_out + 33554436 B) is scratch BEFORE rescore:
//   +12 B          : blkTop u32[N_ROWS*64*8]   (32 MB) per-block top-8 keys
//   +12+32 MB      : ze_bf16 u16[N_ROWS*DIM]   (16.8 MB)
//   then           : cb_bf16 u16[N_EMB*DIM]    ( 8.4 MB)
// Consumed by gemm/merge (stream-ordered before rescore overwrites k_hot).
// ---------------------------------------------------------------------------

typedef short  bhalf8  __attribute__((ext_vector_type(8)));
typedef float  floatx4 __attribute__((ext_vector_type(4)));

__device__ __forceinline__ unsigned short f2b(float f) {
    unsigned u = __builtin_bit_cast(unsigned, f);
    unsigned r = (u + 0x7fffu + ((u >> 16) & 1u)) >> 16;   // RNE
    return (unsigned short)r;
}
__device__ __forceinline__ unsigned pk2(float a, float b) {
    return (unsigned)f2b(a) | ((unsigned)f2b(b) << 16);
}
// sortable key: ascending u32 == ascending (score, col); lower col wins ties
__device__ __forceinline__ unsigned mkkey(float s, int col) {
    unsigned short b = f2b(s);
    unsigned short ts = (unsigned short)(b ^ ((b & 0x8000u) ? 0xFFFFu : 0x8000u));
    return ((unsigned)ts << 16) | (unsigned)col;
}
__device__ __forceinline__ unsigned umn(unsigned a, unsigned b) { return a < b ? a : b; }

// fp32 -> bf16 one-time conversion of both inputs (8 elements/thread).
__global__ void convert_bf16_kernel(const float* __restrict__ ze,
                                    const float* __restrict__ cb,
                                    unsigned short* __restrict__ ze16,
                                    unsigned short* __restrict__ cb16) {
    size_t id = (size_t)blockIdx.x * 256 + threadIdx.x;
    const size_t nze = (size_t)N_ROWS * DIM / 8;
    const float* src;
    unsigned short* dst;
    size_t off;
    if (id < nze) { src = ze; dst = ze16; off = id * 8; }
    else          { src = cb; dst = cb16; off = (id - nze) * 8; }
    float4 a = *(const float4*)(src + off);
    float4 b = *(const float4*)(src + off + 4);
    uint4 u = { pk2(a.x, a.y), pk2(a.z, a.w), pk2(b.x, b.y), pk2(b.z, b.w) };
    *(uint4*)(dst + off) = u;
}

// Phase 1a: bf16 MFMA GEMM fused with per-block per-row top-8.
// 128x128 tile, BK=64. R9 changes vs R8-best:
//   (1) XCD-aware bijective grid swizzle (1D grid of 8192): xcd = bid&7 owns
//       8 consecutive col-tiles -> its B-slice (1 MB) stays L2-resident for
//       the whole kernel; col-tile innermost so each A row-tile gets 7/8 L2
//       hits. Staging LLC traffic ~2.1 GB -> ~150 MB.
//   (2) Double-buffered LDS (64 KB) with prefetch-next-before-compute and
//       COUNTED vmcnt(8) across raw s_barriers (no compiler vmcnt(0) drain):
//       next tile's 8 global_load_lds stay in flight across the barrier and
//       land under the current tile's compute phase.
// Staging swizzle + fragment layout + epilogue identical to R8 (proven).
__launch_bounds__(256, 2)
__global__ void score_gemm_topk_kernel(const unsigned short* __restrict__ ze16,
                                       const unsigned short* __restrict__ cb16,
                                       unsigned* __restrict__ blkTop) {
    __shared__ unsigned short Amm[2][128 * 64];   // 2 x 16 KB
    __shared__ unsigned short Bmm[2][128 * 64];   // 2 x 16 KB

    const int t    = threadIdx.x;
    const int lane = t & 63;
    const int w    = t >> 6;

    // XCD-aware bijective decode (8 XCDs, round-robin dispatch on bid&7):
    // each XCD sweeps row-tiles 0..127 with its 8 col-tiles innermost.
    const int bid   = blockIdx.x;          // 0..8191
    const int xcd   = bid & 7;
    const int chunk = bid >> 3;            // 0..1023
    const int cblk  = xcd * 8 + (chunk & 7);   // col-tile 0..63
    const int rblk  = chunk >> 3;              // row-tile 0..127
    const int rowBase = rblk * 128;
    const int colBase = cblk * 128;

    const int m = lane & 15;
    const int q = lane >> 4;

    floatx4 acc[2][8];
    #pragma unroll
    for (int i = 0; i < 2; ++i)
        #pragma unroll
        for (int j = 0; j < 8; ++j)
            acc[i][j] = (floatx4){0.0f, 0.0f, 0.0f, 0.0f};

    // staging: call k covers tile rows k*32 + (t>>3); phys chunk t&7 holds
    // global chunk (t&7) ^ ((t>>3)&7)
    const int tr = t >> 3;
    const int cg = (t & 7) ^ (tr & 7);
    const unsigned short* pa = ze16 + (size_t)(rowBase + tr) * DIM + cg * 8;
    const unsigned short* pb = cb16 + (size_t)(colBase + tr) * DIM + cg * 8;

    // frag chunk offsets (elements): logical chunk h*4+q, row-swizzle m&7
    const int ch0 = ((0 * 4 + q) ^ (m & 7)) * 8;
    const int ch1 = ((1 * 4 + q) ^ (m & 7)) * 8;

#define STAGE8(buf, koff)                                                             \
    do {                                                                              \
        _Pragma("unroll")                                                             \
        for (int k = 0; k < 4; ++k)                                                   \
            __builtin_amdgcn_global_load_lds(                                         \
                (const GAS void*)(pa + (size_t)k * 32 * DIM + (koff)),                \
                (LAS void*)(&Amm[buf][(k * 256 + w * 64) * 8]), 16, 0, 0);            \
        _Pragma("unroll")                                                             \
        for (int k = 0; k < 4; ++k)                                                   \
            __builtin_amdgcn_global_load_lds(                                         \
                (const GAS void*)(pb + (size_t)k * 32 * DIM + (koff)),                \
                (LAS void*)(&Bmm[buf][(k * 256 + w * 64) * 8]), 16, 0, 0);            \
    } while (0)

    // prologue: stage tile 0 (8 loads/thread in flight)
    STAGE8(0, 0);

    int cur = 0;
    #pragma unroll 1
    for (int t8 = 0; t8 < 8; ++t8) {
        // issue next tile into the other buffer, then wait only for the
        // CURRENT tile's 8 loads (oldest); next tile's stay in flight.
        if (t8 < 7) {
            STAGE8(cur ^ 1, (t8 + 1) * 64);
            asm volatile("s_waitcnt vmcnt(8)" ::: "memory");
        } else {
            asm volatile("s_waitcnt vmcnt(0)" ::: "memory");
        }
        __builtin_amdgcn_s_barrier();   // raw: no compiler vmcnt(0) drain

        #pragma unroll
        for (int h = 0; h < 2; ++h) {
            const int ch = h ? ch1 : ch0;
            bhalf8 af0 = *(bhalf8*)&Amm[cur][(w * 32 + m) * 64 + ch];
            bhalf8 af1 = *(bhalf8*)&Amm[cur][(w * 32 + 16 + m) * 64 + ch];
            #pragma unroll
            for (int j = 0; j < 8; ++j) {
                bhalf8 bf = *(bhalf8*)&Bmm[cur][(j * 16 + m) * 64 + ch];
                acc[0][j] = __builtin_amdgcn_mfma_f32_16x16x32_bf16(af0, bf, acc[0][j], 0, 0, 0);
                acc[1][j] = __builtin_amdgcn_mfma_f32_16x16x32_bf16(af1, bf, acc[1][j], 0, 0, 0);
            }
        }
        // all waves done reading buf[cur] before it is re-staged next iter
        __builtin_amdgcn_s_barrier();
        cur ^= 1;
    }
#undef STAGE8

    // Epilogue (proven R7/R8). C/D layout: col = lane&15, row = quad*4 + reg.
    #pragma unroll
    for (int i = 0; i < 2; ++i) {
        #pragma unroll
        for (int reg = 0; reg < 4; ++reg) {
            const int grow = rowBase + w * 32 + i * 16 + q * 4 + reg;
            unsigned kk[8];
            #pragma unroll
            for (int j = 0; j < 8; ++j) {
                unsigned e = mkkey(-acc[i][j][reg], colBase + j * 16 + m);
                kk[j] = e;
                #pragma unroll
                for (int s = 7; s > 0; --s) {
                    if (s <= j) {
                        unsigned lo = umn(kk[s - 1], kk[s]);
                        unsigned hi = kk[s - 1] < kk[s] ? kk[s] : kk[s - 1];
                        kk[s - 1] = lo; kk[s] = hi;
                    }
                }
            }
            unsigned sval = 0;
            #pragma unroll
            for (int s = 0; s < 8; ++s) {
                unsigned g = kk[0];
                g = umn(g, (unsigned)__shfl_xor((int)g, 1, 64));
                g = umn(g, (unsigned)__shfl_xor((int)g, 2, 64));
                g = umn(g, (unsigned)__shfl_xor((int)g, 4, 64));
                g = umn(g, (unsigned)__shfl_xor((int)g, 8, 64));
                bool pop = (kk[0] == g);
                #pragma unroll
                for (int u = 0; u < 7; ++u) kk[u] = pop ? kk[u + 1] : kk[u];
                kk[7] = pop ? 0xFFFFFFFFu : kk[7];
                sval = (m == s) ? g : sval;
            }
            if (m < 8)
                blkTop[((size_t)grow * 64 + cblk) * 8 + m] = sval;
        }
    }
}

// Phase 1b: merge 64 blocks x 8 keys per row -> top-16 candidates.
__global__ void merge_topk_kernel(const unsigned* __restrict__ blkTop,
                                  int* __restrict__ cand) {
    const int wv   = threadIdx.x >> 6;
    const int lane = threadIdx.x & 63;
    const int row  = blockIdx.x * 4 + wv;
    const uint4* base = (const uint4*)(blkTop + (size_t)row * 512);

    uint4 a = base[lane * 2];
    uint4 b = base[lane * 2 + 1];
    unsigned in[8] = { a.x, a.y, a.z, a.w, b.x, b.y, b.z, b.w };
    unsigned kk[8];
    #pragma unroll
    for (int j = 0; j < 8; ++j) {
        kk[j] = in[j];
        #pragma unroll
        for (int s = 7; s > 0; --s) {
            if (s <= j) {
                unsigned lo = umn(kk[s - 1], kk[s]);
                unsigned hi = kk[s - 1] < kk[s] ? kk[s] : kk[s - 1];
                kk[s - 1] = lo; kk[s] = hi;
            }
        }
    }

    unsigned sval = 0;
    #pragma unroll
    for (int s = 0; s < NCAND; ++s) {
        unsigned g = kk[0];
        #pragma unroll
        for (int d = 32; d; d >>= 1)
            g = umn(g, (unsigned)__shfl_xor((int)g, d, 64));
        bool pop = (kk[0] == g);
        #pragma unroll
        for (int u = 0; u < 7; ++u) kk[u] = pop ? kk[u + 1] : kk[u];
        kk[7] = pop ? 0xFFFFFFFFu : kk[7];
        sval = (lane == s) ? g : sval;
    }
    if (lane < NCAND)
        cand[(size_t)row * NCAND + lane] = (int)(sval & 0xFFFFu);
}

// Phase 2: exact numpy-fp32 replica rescore (selection logic unchanged since
// R4) + FULL k_hot row write (zeros + the 4 ones in one pass; replaces the
// 512 MB memset).
__global__ void rescore_kernel(const float* __restrict__ ze,
                               const float* __restrict__ cb,
                               const int* __restrict__ cand,
                               float* __restrict__ out_zq,
                               float* __restrict__ out_khot,
                               double* __restrict__ lossAcc) {
    __shared__ float zsh[4][DIM];
    const int wv = threadIdx.x >> 6;
    const int lane = threadIdx.x & 63;
    const int row = blockIdx.x * 4 + wv;

    {
        const float* zp = ze + (size_t)row * DIM + lane * 8;
        float4 v0 = *(const float4*)zp;
        float4 v1 = *(const float4*)(zp + 4);
        *(float4*)&zsh[wv][lane * 8]     = v0;
        *(float4*)&zsh[wv][lane * 8 + 4] = v1;
    }
    __syncthreads();

    // znorm, numpy-pairwise
    float racc = 0.0f;
    {
        const int b = (lane >> 3) & 3;
        const int j = lane & 7;
        const float* zr = &zsh[wv][128 * b + j];
        #pragma unroll
        for (int i = 0; i < 16; ++i) {
            float zk = zr[8 * i];
            float sq = zk * zk;
            asm volatile("" : "+v"(sq));   // block FMA contraction into the add
            racc = racc + sq;
        }
    }
    float t1 = racc + __shfl_xor(racc, 1, 64);
    float t2 = t1 + __shfl_xor(t1, 2, 64);
    float t3 = t2 + __shfl_xor(t2, 4, 64);
    float zn = (__shfl(t3, 0, 64) + __shfl(t3, 8, 64))
             + (__shfl(t3, 16, 64) + __shfl(t3, 24, 64));

    // candidate chains: KC=384 split, sequential FMA, single accumulator each
    float qv = 3.0e38f;
    int   idxv = 0x7fffffff;
    if (lane < NCAND) {
        idxv = cand[(size_t)row * NCAND + lane];
        const float* wp = cb + (size_t)idxv * DIM;
        const float* zz = zsh[wv];
        float acc1 = 0.0f;
        for (int k = 0; k < 384; k += 8) {
            float4 wa = *(const float4*)(wp + k);
            float4 wb = *(const float4*)(wp + k + 4);
            acc1 = __builtin_fmaf(zz[k + 0], wa.x, acc1);
            acc1 = __builtin_fmaf(zz[k + 1], wa.y, acc1);
            acc1 = __builtin_fmaf(zz[k + 2], wa.z, acc1);
            acc1 = __builtin_fmaf(zz[k + 3], wa.w, acc1);
            acc1 = __builtin_fmaf(zz[k + 4], wb.x, acc1);
            acc1 = __builtin_fmaf(zz[k + 5], wb.y, acc1);
            acc1 = __builtin_fmaf(zz[k + 6], wb.z, acc1);
            acc1 = __builtin_fmaf(zz[k + 7], wb.w, acc1);
        }
        float acc2 = 0.0f;
        for (int k = 384; k < 512; k += 8) {
            float4 wa = *(const float4*)(wp + k);
            float4 wb = *(const float4*)(wp + k + 4);
            acc2 = __builtin_fmaf(zz[k + 0], wa.x, acc2);
            acc2 = __builtin_fmaf(zz[k + 1], wa.y, acc2);
            acc2 = __builtin_fmaf(zz[k + 2], wa.z, acc2);
            acc2 = __builtin_fmaf(zz[k + 3], wa.w, acc2);
            acc2 = __builtin_fmaf(zz[k + 4], wb.x, acc2);
            acc2 = __builtin_fmaf(zz[k + 5], wb.y, acc2);
            acc2 = __builtin_fmaf(zz[k + 6], wb.z, acc2);
            acc2 = __builtin_fmaf(zz[k + 7], wb.w, acc2);
        }
        float Cv = acc1 + acc2;
        qv = zn - 2.0f * Cv;
    }

    float q[NCAND]; int id[NCAND];
    #pragma unroll
    for (int c = 0; c < NCAND; ++c) {
        q[c]  = __shfl(qv, c, 64);
        id[c] = __shfl(idxv, c, 64);
    }
    int selIdx[4];
    bool used[NCAND];
    #pragma unroll
    for (int c = 0; c < NCAND; ++c) used[c] = false;
    #pragma unroll
    for (int s = 0; s < 4; ++s) {
        float bq = 3.0e38f; int bi = 0x7fffffff; int bc = -1;
        #pragma unroll
        for (int c = 0; c < NCAND; ++c) {
            bool better = !used[c] && (q[c] < bq || (q[c] == bq && id[c] < bi));
            if (better) { bq = q[c]; bi = id[c]; bc = c; }
        }
        selIdx[s] = bi;
        #pragma unroll
        for (int c = 0; c < NCAND; ++c) used[c] = used[c] || (c == bc);
    }

    float zq[8] = { 0, 0, 0, 0, 0, 0, 0, 0 };
    #pragma unroll
    for (int s = 0; s < 4; ++s) {
        const float* wp = cb + (size_t)selIdx[s] * DIM + lane * 8;
        float4 w0 = *(const float4*)wp;
        float4 w1 = *(const float4*)(wp + 4);
        zq[0] += w0.x; zq[1] += w0.y; zq[2] += w0.z; zq[3] += w0.w;
        zq[4] += w1.x; zq[5] += w1.y; zq[6] += w1.z; zq[7] += w1.w;
    }

    float zf[8];
    {
        const float* zz = &zsh[wv][lane * 8];
        #pragma unroll
        for (int i = 0; i < 8; ++i) zf[i] = zz[i];
    }
    float o[8];
    double l = 0.0;
    #pragma unroll
    for (int i = 0; i < 8; ++i) {
        float zqf  = zq[i] * 0.25f;
        float diff = zqf - zf[i];
        o[i] = zf[i] + diff;
        double ld = (double)diff;
        l += ld * ld;
    }
    {
        float* op = out_zq + (size_t)row * DIM + lane * 8;
        float4 v0 = { o[0], o[1], o[2], o[3] };
        float4 v1 = { o[4], o[5], o[6], o[7] };
        *(float4*)op = v0;
        *(float4*)(op + 4) = v1;
    }
    #pragma unroll
    for (int mm = 32; mm; mm >>= 1) l += __shfl_xor(l, mm, 64);
    if (lane == 0) atomicAdd(lossAcc, l);

    // full k_hot row write: lane owns cols {j*256 + lane*4 + e}.
    // hot mask: col -> j = col>>8, e = col&3, owner lane = (col>>2)&63.
    unsigned hotm[4] = { 0u, 0u, 0u, 0u };
    #pragma unroll
    for (int s = 0; s < 4; ++s) {
        int si = selIdx[s];
        bool own = ((si >> 2) & 63) == lane;
        int jj = si >> 8;
        unsigned bit = 1u << (((jj & 7) << 2) | (si & 3));
        int word = jj >> 3;
        #pragma unroll
        for (int wd = 0; wd < 4; ++wd)
            hotm[wd] |= (own && word == wd) ? bit : 0u;
    }
    float* kp = out_khot + (size_t)row * N_EMB;
    #pragma unroll
    for (int j = 0; j < 32; ++j) {
        unsigned bits = (hotm[j >> 3] >> ((j & 7) * 4)) & 0xFu;
        float4 v;
        v.x = (bits & 1u) ? 1.0f : 0.0f;
        v.y = (bits & 2u) ? 1.0f : 0.0f;
        v.z = (bits & 4u) ? 1.0f : 0.0f;
        v.w = (bits & 8u) ? 1.0f : 0.0f;
        *(float4*)(kp + j * 256 + lane * 4) = v;
    }
}

__global__ void finalize_kernel(const double* __restrict__ lossAcc,
                                float* __restrict__ out_loss) {
    if (threadIdx.x == 0 && blockIdx.x == 0)
        out_loss[0] = (float)(lossAcc[0] * (1.25 / ((double)N_ROWS * (double)DIM)));
}

extern "C" void kernel_launch(void* const* d_in, const int* in_sizes, int n_in,
                              void* d_out, int out_size, void* d_ws, size_t ws_size,
                              hipStream_t stream) {
    (void)in_sizes; (void)n_in; (void)out_size; (void)ws_size;
    const float* ze = (const float*)d_in[0];
    const float* cb = (const float*)d_in[1];

    float* out      = (float*)d_out;
    float* out_zq   = out;                                   // [16384, 512]
    float* out_loss = out + (size_t)N_ROWS * DIM;            // [1]
    float* out_khot = out_loss + 1;                          // [16384, 8192]

    double* lossAcc = (double*)d_ws;
    int*    cand    = (int*)((char*)d_ws + 16);

    // scratch inside k_hot region, 16B-aligned, consumed before rescore
    char* base = (char*)d_out;
    unsigned*       blkTop = (unsigned*)(base + 33554448);                  // khot + 12 B
    unsigned short* ze16   = (unsigned short*)(base + 33554448 + 33554432); // + 32 MB
    unsigned short* cb16   = ze16 + (size_t)N_ROWS * DIM;

    hipMemsetAsync(lossAcc, 0, 16, stream);

    convert_bf16_kernel<<<6144, 256, 0, stream>>>(ze, cb, ze16, cb16);
    score_gemm_topk_kernel<<<8192, 256, 0, stream>>>(ze16, cb16, blkTop);
    merge_topk_kernel<<<N_ROWS / 4, 256, 0, stream>>>(blkTop, cand);
    rescore_kernel<<<N_ROWS / 4, 256, 0, stream>>>(ze, cb, cand, out_zq, out_khot, lossAcc);
    finalize_kernel<<<1, 64, 0, stream>>>(lossAcc, out_loss);
}

// Round 2
// 1012.549 us; speedup vs baseline: 1.0771x; 1.0771x over previous
//
#include <hip/hip_runtime.h>

#define N_ROWS 16384
#define N_EMB  8192
#define DIM    512
#define NCAND  16

#define GAS __attribute__((address_space(1)))
#define LAS __attribute__((address_space(3)))

// ---------------------------------------------------------------------------
// ws layout:
//   [0]    double lossAcc (16 B, zeroed)
//   [16]   int cand[N_ROWS * NCAND]   (1 MB)
// k_hot region (512 MB at d_out + 33554436 B) is scratch BEFORE rescore:
//   +12 B          : blkTop u32[N_ROWS*64*8]   (32 MB) per-block top-8 keys
//   +12+32 MB      : ze_bf16 u16[N_ROWS*DIM]   (16.8 MB)
//   then           : cb_bf16 u16[N_EMB*DIM]    ( 8.4 MB)
// Consumed by gemm/merge (stream-ordered before rescore overwrites k_hot).
// ---------------------------------------------------------------------------

typedef short  bhalf8  __attribute__((ext_vector_type(8)));
typedef float  floatx4 __attribute__((ext_vector_type(4)));

__device__ __forceinline__ unsigned short f2b(float f) {
    unsigned u = __builtin_bit_cast(unsigned, f);
    unsigned r = (u + 0x7fffu + ((u >> 16) & 1u)) >> 16;   // RNE
    return (unsigned short)r;
}
__device__ __forceinline__ unsigned pk2(float a, float b) {
    return (unsigned)f2b(a) | ((unsigned)f2b(b) << 16);
}
// sortable key: ascending u32 == ascending (score, col); lower col wins ties
__device__ __forceinline__ unsigned mkkey(float s, int col) {
    unsigned short b = f2b(s);
    unsigned short ts = (unsigned short)(b ^ ((b & 0x8000u) ? 0xFFFFu : 0x8000u));
    return ((unsigned)ts << 16) | (unsigned)col;
}
__device__ __forceinline__ unsigned umn(unsigned a, unsigned b) { return a < b ? a : b; }

// fp32 -> bf16 one-time conversion of both inputs (8 elements/thread).
__global__ void convert_bf16_kernel(const float* __restrict__ ze,
                                    const float* __restrict__ cb,
                                    unsigned short* __restrict__ ze16,
                                    unsigned short* __restrict__ cb16) {
    size_t id = (size_t)blockIdx.x * 256 + threadIdx.x;
    const size_t nze = (size_t)N_ROWS * DIM / 8;
    const float* src;
    unsigned short* dst;
    size_t off;
    if (id < nze) { src = ze; dst = ze16; off = id * 8; }
    else          { src = cb; dst = cb16; off = (id - nze) * 8; }
    float4 a = *(const float4*)(src + off);
    float4 b = *(const float4*)(src + off + 4);
    uint4 u = { pk2(a.x, a.y), pk2(a.z, a.w), pk2(b.x, b.y), pk2(b.z, b.w) };
    *(uint4*)(dst + off) = u;
}

// Phase 1a: bf16 MFMA GEMM fused with per-block per-row top-8.
// R10 = R8-proven single-buffer m97 structure (3 blocks/CU, compiler
// __syncthreads) + R9's proven XCD-aware bijective grid swizzle.
// R9 post-mortem: swizzle cut GEMM HBM fetch to 68 MB (staging now
// L2-resident), but 64KB double-buffer + rolled loop + raw barriers dropped
// occupancy 3->2 blocks/CU and killed compiler cross-iteration scheduling
// (MfmaUtil 16.6%, dur 359us). Revert structure, keep swizzle.
// 128x128 tile, BK=64 (8 K-iters). Staging via global_load_lds width=16,
// unpadded row-major [128][64] bf16 (128 B rows = 8 chunks); XOR swizzle
// c_phys = c_log ^ (r&7). All fragment rows satisfy r&7 == m&7, so frag
// reads spread evenly over all 8 bank-quads.
__launch_bounds__(256, 3)
__global__ void score_gemm_topk_kernel(const unsigned short* __restrict__ ze16,
                                       const unsigned short* __restrict__ cb16,
                                       unsigned* __restrict__ blkTop) {
    __shared__ unsigned short Amm[128 * 64];   // 16 KB
    __shared__ unsigned short Bmm[128 * 64];   // 16 KB

    const int t    = threadIdx.x;
    const int lane = t & 63;
    const int w    = t >> 6;

    // XCD-aware bijective decode (8 XCDs, round-robin dispatch on bid&7):
    // each XCD owns 8 consecutive col-tiles (1 MB B-slice, L2-resident) and
    // sweeps row-tiles with its col-tiles innermost.
    const int bid   = blockIdx.x;              // 0..8191
    const int xcd   = bid & 7;
    const int chunk = bid >> 3;                // 0..1023
    const int cblk  = xcd * 8 + (chunk & 7);   // col-tile 0..63
    const int rblk  = chunk >> 3;              // row-tile 0..127
    const int rowBase = rblk * 128;
    const int colBase = cblk * 128;

    const int m = lane & 15;
    const int q = lane >> 4;

    floatx4 acc[2][8];
    #pragma unroll
    for (int i = 0; i < 2; ++i)
        #pragma unroll
        for (int j = 0; j < 8; ++j)
            acc[i][j] = (floatx4){0.0f, 0.0f, 0.0f, 0.0f};

    // staging: call k covers tile rows k*32 + (t>>3); phys chunk t&7 holds
    // global chunk (t&7) ^ ((t>>3)&7)
    const int tr = t >> 3;
    const int cg = (t & 7) ^ (tr & 7);
    const unsigned short* pa = ze16 + (size_t)(rowBase + tr) * DIM + cg * 8;
    const unsigned short* pb = cb16 + (size_t)(colBase + tr) * DIM + cg * 8;

    // frag chunk offsets (elements): logical chunk h*4+q, row-swizzle m&7
    const int ch0 = ((0 * 4 + q) ^ (m & 7)) * 8;
    const int ch1 = ((1 * 4 + q) ^ (m & 7)) * 8;

    for (int k0 = 0; k0 < DIM; k0 += 64) {
        __syncthreads();
        #pragma unroll
        for (int k = 0; k < 4; ++k)
            __builtin_amdgcn_global_load_lds((const GAS void*)(pa + (size_t)k * 32 * DIM + k0),
                                             (LAS void*)(Amm + (k * 256 + w * 64) * 8), 16, 0, 0);
        #pragma unroll
        for (int k = 0; k < 4; ++k)
            __builtin_amdgcn_global_load_lds((const GAS void*)(pb + (size_t)k * 32 * DIM + k0),
                                             (LAS void*)(Bmm + (k * 256 + w * 64) * 8), 16, 0, 0);
        __syncthreads();

        #pragma unroll
        for (int h = 0; h < 2; ++h) {
            const int ch = h ? ch1 : ch0;
            bhalf8 af0 = *(bhalf8*)&Amm[(w * 32 + m) * 64 + ch];
            bhalf8 af1 = *(bhalf8*)&Amm[(w * 32 + 16 + m) * 64 + ch];
            #pragma unroll
            for (int j = 0; j < 8; ++j) {
                bhalf8 bf = *(bhalf8*)&Bmm[(j * 16 + m) * 64 + ch];
                acc[0][j] = __builtin_amdgcn_mfma_f32_16x16x32_bf16(af0, bf, acc[0][j], 0, 0, 0);
                acc[1][j] = __builtin_amdgcn_mfma_f32_16x16x32_bf16(af1, bf, acc[1][j], 0, 0, 0);
            }
        }
    }

    // Epilogue (proven R7/R8). C/D layout: col = lane&15, row = quad*4 + reg.
    #pragma unroll
    for (int i = 0; i < 2; ++i) {
        #pragma unroll
        for (int reg = 0; reg < 4; ++reg) {
            const int grow = rowBase + w * 32 + i * 16 + q * 4 + reg;
            unsigned kk[8];
            #pragma unroll
            for (int j = 0; j < 8; ++j) {
                unsigned e = mkkey(-acc[i][j][reg], colBase + j * 16 + m);
                kk[j] = e;
                #pragma unroll
                for (int s = 7; s > 0; --s) {
                    if (s <= j) {
                        unsigned lo = umn(kk[s - 1], kk[s]);
                        unsigned hi = kk[s - 1] < kk[s] ? kk[s] : kk[s - 1];
                        kk[s - 1] = lo; kk[s] = hi;
                    }
                }
            }
            unsigned sval = 0;
            #pragma unroll
            for (int s = 0; s < 8; ++s) {
                unsigned g = kk[0];
                g = umn(g, (unsigned)__shfl_xor((int)g, 1, 64));
                g = umn(g, (unsigned)__shfl_xor((int)g, 2, 64));
                g = umn(g, (unsigned)__shfl_xor((int)g, 4, 64));
                g = umn(g, (unsigned)__shfl_xor((int)g, 8, 64));
                bool pop = (kk[0] == g);
                #pragma unroll
                for (int u = 0; u < 7; ++u) kk[u] = pop ? kk[u + 1] : kk[u];
                kk[7] = pop ? 0xFFFFFFFFu : kk[7];
                sval = (m == s) ? g : sval;
            }
            if (m < 8)
                blkTop[((size_t)grow * 64 + cblk) * 8 + m] = sval;
        }
    }
}

// Phase 1b: merge 64 blocks x 8 keys per row -> top-16 candidates.
__global__ void merge_topk_kernel(const unsigned* __restrict__ blkTop,
                                  int* __restrict__ cand) {
    const int wv   = threadIdx.x >> 6;
    const int lane = threadIdx.x & 63;
    const int row  = blockIdx.x * 4 + wv;
    const uint4* base = (const uint4*)(blkTop + (size_t)row * 512);

    uint4 a = base[lane * 2];
    uint4 b = base[lane * 2 + 1];
    unsigned in[8] = { a.x, a.y, a.z, a.w, b.x, b.y, b.z, b.w };
    unsigned kk[8];
    #pragma unroll
    for (int j = 0; j < 8; ++j) {
        kk[j] = in[j];
        #pragma unroll
        for (int s = 7; s > 0; --s) {
            if (s <= j) {
                unsigned lo = umn(kk[s - 1], kk[s]);
                unsigned hi = kk[s - 1] < kk[s] ? kk[s] : kk[s - 1];
                kk[s - 1] = lo; kk[s] = hi;
            }
        }
    }

    unsigned sval = 0;
    #pragma unroll
    for (int s = 0; s < NCAND; ++s) {
        unsigned g = kk[0];
        #pragma unroll
        for (int d = 32; d; d >>= 1)
            g = umn(g, (unsigned)__shfl_xor((int)g, d, 64));
        bool pop = (kk[0] == g);
        #pragma unroll
        for (int u = 0; u < 7; ++u) kk[u] = pop ? kk[u + 1] : kk[u];
        kk[7] = pop ? 0xFFFFFFFFu : kk[7];
        sval = (lane == s) ? g : sval;
    }
    if (lane < NCAND)
        cand[(size_t)row * NCAND + lane] = (int)(sval & 0xFFFFu);
}

// Phase 2: exact numpy-fp32 replica rescore (selection logic unchanged since
// R4) + FULL k_hot row write (zeros + the 4 ones in one pass; replaces the
// 512 MB memset).
__global__ void rescore_kernel(const float* __restrict__ ze,
                               const float* __restrict__ cb,
                               const int* __restrict__ cand,
                               float* __restrict__ out_zq,
                               float* __restrict__ out_khot,
                               double* __restrict__ lossAcc) {
    __shared__ float zsh[4][DIM];
    const int wv = threadIdx.x >> 6;
    const int lane = threadIdx.x & 63;
    const int row = blockIdx.x * 4 + wv;

    {
        const float* zp = ze + (size_t)row * DIM + lane * 8;
        float4 v0 = *(const float4*)zp;
        float4 v1 = *(const float4*)(zp + 4);
        *(float4*)&zsh[wv][lane * 8]     = v0;
        *(float4*)&zsh[wv][lane * 8 + 4] = v1;
    }
    __syncthreads();

    // znorm, numpy-pairwise
    float racc = 0.0f;
    {
        const int b = (lane >> 3) & 3;
        const int j = lane & 7;
        const float* zr = &zsh[wv][128 * b + j];
        #pragma unroll
        for (int i = 0; i < 16; ++i) {
            float zk = zr[8 * i];
            float sq = zk * zk;
            asm volatile("" : "+v"(sq));   // block FMA contraction into the add
            racc = racc + sq;
        }
    }
    float t1 = racc + __shfl_xor(racc, 1, 64);
    float t2 = t1 + __shfl_xor(t1, 2, 64);
    float t3 = t2 + __shfl_xor(t2, 4, 64);
    float zn = (__shfl(t3, 0, 64) + __shfl(t3, 8, 64))
             + (__shfl(t3, 16, 64) + __shfl(t3, 24, 64));

    // candidate chains: KC=384 split, sequential FMA, single accumulator each
    float qv = 3.0e38f;
    int   idxv = 0x7fffffff;
    if (lane < NCAND) {
        idxv = cand[(size_t)row * NCAND + lane];
        const float* wp = cb + (size_t)idxv * DIM;
        const float* zz = zsh[wv];
        float acc1 = 0.0f;
        for (int k = 0; k < 384; k += 8) {
            float4 wa = *(const float4*)(wp + k);
            float4 wb = *(const float4*)(wp + k + 4);
            acc1 = __builtin_fmaf(zz[k + 0], wa.x, acc1);
            acc1 = __builtin_fmaf(zz[k + 1], wa.y, acc1);
            acc1 = __builtin_fmaf(zz[k + 2], wa.z, acc1);
            acc1 = __builtin_fmaf(zz[k + 3], wa.w, acc1);
            acc1 = __builtin_fmaf(zz[k + 4], wb.x, acc1);
            acc1 = __builtin_fmaf(zz[k + 5], wb.y, acc1);
            acc1 = __builtin_fmaf(zz[k + 6], wb.z, acc1);
            acc1 = __builtin_fmaf(zz[k + 7], wb.w, acc1);
        }
        float acc2 = 0.0f;
        for (int k = 384; k < 512; k += 8) {
            float4 wa = *(const float4*)(wp + k);
            float4 wb = *(const float4*)(wp + k + 4);
            acc2 = __builtin_fmaf(zz[k + 0], wa.x, acc2);
            acc2 = __builtin_fmaf(zz[k + 1], wa.y, acc2);
            acc2 = __builtin_fmaf(zz[k + 2], wa.z, acc2);
            acc2 = __builtin_fmaf(zz[k + 3], wa.w, acc2);
            acc2 = __builtin_fmaf(zz[k + 4], wb.x, acc2);
            acc2 = __builtin_fmaf(zz[k + 5], wb.y, acc2);
            acc2 = __builtin_fmaf(zz[k + 6], wb.z, acc2);
            acc2 = __builtin_fmaf(zz[k + 7], wb.w, acc2);
        }
        float Cv = acc1 + acc2;
        qv = zn - 2.0f * Cv;
    }

    float q[NCAND]; int id[NCAND];
    #pragma unroll
    for (int c = 0; c < NCAND; ++c) {
        q[c]  = __shfl(qv, c, 64);
        id[c] = __shfl(idxv, c, 64);
    }
    int selIdx[4];
    bool used[NCAND];
    #pragma unroll
    for (int c = 0; c < NCAND; ++c) used[c] = false;
    #pragma unroll
    for (int s = 0; s < 4; ++s) {
        float bq = 3.0e38f; int bi = 0x7fffffff; int bc = -1;
        #pragma unroll
        for (int c = 0; c < NCAND; ++c) {
            bool better = !used[c] && (q[c] < bq || (q[c] == bq && id[c] < bi));
            if (better) { bq = q[c]; bi = id[c]; bc = c; }
        }
        selIdx[s] = bi;
        #pragma unroll
        for (int c = 0; c < NCAND; ++c) used[c] = used[c] || (c == bc);
    }

    float zq[8] = { 0, 0, 0, 0, 0, 0, 0, 0 };
    #pragma unroll
    for (int s = 0; s < 4; ++s) {
        const float* wp = cb + (size_t)selIdx[s] * DIM + lane * 8;
        float4 w0 = *(const float4*)wp;
        float4 w1 = *(const float4*)(wp + 4);
        zq[0] += w0.x; zq[1] += w0.y; zq[2] += w0.z; zq[3] += w0.w;
        zq[4] += w1.x; zq[5] += w1.y; zq[6] += w1.z; zq[7] += w1.w;
    }

    float zf[8];
    {
        const float* zz = &zsh[wv][lane * 8];
        #pragma unroll
        for (int i = 0; i < 8; ++i) zf[i] = zz[i];
    }
    float o[8];
    double l = 0.0;
    #pragma unroll
    for (int i = 0; i < 8; ++i) {
        float zqf  = zq[i] * 0.25f;
        float diff = zqf - zf[i];
        o[i] = zf[i] + diff;
        double ld = (double)diff;
        l += ld * ld;
    }
    {
        float* op = out_zq + (size_t)row * DIM + lane * 8;
        float4 v0 = { o[0], o[1], o[2], o[3] };
        float4 v1 = { o[4], o[5], o[6], o[7] };
        *(float4*)op = v0;
        *(float4*)(op + 4) = v1;
    }
    #pragma unroll
    for (int mm = 32; mm; mm >>= 1) l += __shfl_xor(l, mm, 64);
    if (lane == 0) atomicAdd(lossAcc, l);

    // full k_hot row write: lane owns cols {j*256 + lane*4 + e}.
    // hot mask: col -> j = col>>8, e = col&3, owner lane = (col>>2)&63.
    unsigned hotm[4] = { 0u, 0u, 0u, 0u };
    #pragma unroll
    for (int s = 0; s < 4; ++s) {
        int si = selIdx[s];
        bool own = ((si >> 2) & 63) == lane;
        int jj = si >> 8;
        unsigned bit = 1u << (((jj & 7) << 2) | (si & 3));
        int word = jj >> 3;
        #pragma unroll
        for (int wd = 0; wd < 4; ++wd)
            hotm[wd] |= (own && word == wd) ? bit : 0u;
    }
    float* kp = out_khot + (size_t)row * N_EMB;
    #pragma unroll
    for (int j = 0; j < 32; ++j) {
        unsigned bits = (hotm[j >> 3] >> ((j & 7) * 4)) & 0xFu;
        float4 v;
        v.x = (bits & 1u) ? 1.0f : 0.0f;
        v.y = (bits & 2u) ? 1.0f : 0.0f;
        v.z = (bits & 4u) ? 1.0f : 0.0f;
        v.w = (bits & 8u) ? 1.0f : 0.0f;
        *(float4*)(kp + j * 256 + lane * 4) = v;
    }
}

__global__ void finalize_kernel(const double* __restrict__ lossAcc,
                                float* __restrict__ out_loss) {
    if (threadIdx.x == 0 && blockIdx.x == 0)
        out_loss[0] = (float)(lossAcc[0] * (1.25 / ((double)N_ROWS * (double)DIM)));
}

extern "C" void kernel_launch(void* const* d_in, const int* in_sizes, int n_in,
                              void* d_out, int out_size, void* d_ws, size_t ws_size,
                              hipStream_t stream) {
    (void)in_sizes; (void)n_in; (void)out_size; (void)ws_size;
    const float* ze = (const float*)d_in[0];
    const float* cb = (const float*)d_in[1];

    float* out      = (float*)d_out;
    float* out_zq   = out;                                   // [16384, 512]
    float* out_loss = out + (size_t)N_ROWS * DIM;            // [1]
    float* out_khot = out_loss + 1;                          // [16384, 8192]

    double* lossAcc = (double*)d_ws;
    int*    cand    = (int*)((char*)d_ws + 16);

    // scratch inside k_hot region, 16B-aligned, consumed before rescore
    char* base = (char*)d_out;
    unsigned*       blkTop = (unsigned*)(base + 33554448);                  // khot + 12 B
    unsigned short* ze16   = (unsigned short*)(base + 33554448 + 33554432); // + 32 MB
    unsigned short* cb16   = ze16 + (size_t)N_ROWS * DIM;

    hipMemsetAsync(lossAcc, 0, 16, stream);

    convert_bf16_kernel<<<6144, 256, 0, stream>>>(ze, cb, ze16, cb16);
    score_gemm_topk_kernel<<<8192, 256, 0, stream>>>(ze16, cb16, blkTop);
    merge_topk_kernel<<<N_ROWS / 4, 256, 0, stream>>>(blkTop, cand);
    rescore_kernel<<<N_ROWS / 4, 256, 0, stream>>>(ze, cb, cand, out_zq, out_khot, lossAcc);
    finalize_kernel<<<1, 64, 0, stream>>>(lossAcc, out_loss);
}

// Round 3
// 1002.869 us; speedup vs baseline: 1.0875x; 1.0097x over previous
//
#include <hip/hip_runtime.h>

#define N_ROWS 16384
#define N_EMB  8192
#define DIM    512
#define NCAND  16

#define GAS __attribute__((address_space(1)))
#define LAS __attribute__((address_space(3)))

// ---------------------------------------------------------------------------
// ws layout:
//   [0]    double lossAcc (16 B, zeroed)
//   [16]   int cand[N_ROWS * NCAND]   (1 MB)
// k_hot region (512 MB at d_out + 33554436 B) is scratch BEFORE rescore:
//   +12 B          : blkTop u32[N_ROWS*64*8]   (32 MB) per-block top-8 keys
//   +12+32 MB      : ze_bf16 u16[N_ROWS*DIM]   (16.8 MB)
//   then           : cb_bf16 u16[N_EMB*DIM]    ( 8.4 MB)
// Consumed by gemm/merge (stream-ordered before rescore overwrites k_hot).
// ---------------------------------------------------------------------------

typedef short  bhalf8  __attribute__((ext_vector_type(8)));
typedef float  floatx4 __attribute__((ext_vector_type(4)));

__device__ __forceinline__ unsigned short f2b(float f) {
    unsigned u = __builtin_bit_cast(unsigned, f);
    unsigned r = (u + 0x7fffu + ((u >> 16) & 1u)) >> 16;   // RNE
    return (unsigned short)r;
}
__device__ __forceinline__ unsigned pk2(float a, float b) {
    return (unsigned)f2b(a) | ((unsigned)f2b(b) << 16);
}
// sortable key: ascending u32 == ascending (score, col); lower col wins ties
__device__ __forceinline__ unsigned mkkey(float s, int col) {
    unsigned short b = f2b(s);
    unsigned short ts = (unsigned short)(b ^ ((b & 0x8000u) ? 0xFFFFu : 0x8000u));
    return ((unsigned)ts << 16) | (unsigned)col;
}
__device__ __forceinline__ unsigned umn(unsigned a, unsigned b) { return a < b ? a : b; }

// fp32 -> bf16 one-time conversion of both inputs (8 elements/thread).
__global__ void convert_bf16_kernel(const float* __restrict__ ze,
                                    const float* __restrict__ cb,
                                    unsigned short* __restrict__ ze16,
                                    unsigned short* __restrict__ cb16) {
    size_t id = (size_t)blockIdx.x * 256 + threadIdx.x;
    const size_t nze = (size_t)N_ROWS * DIM / 8;
    const float* src;
    unsigned short* dst;
    size_t off;
    if (id < nze) { src = ze; dst = ze16; off = id * 8; }
    else          { src = cb; dst = cb16; off = (id - nze) * 8; }
    float4 a = *(const float4*)(src + off);
    float4 b = *(const float4*)(src + off + 4);
    uint4 u = { pk2(a.x, a.y), pk2(a.z, a.w), pk2(b.x, b.y), pk2(b.z, b.w) };
    *(uint4*)(dst + off) = u;
}

// Phase 1a: bf16 MFMA GEMM fused with per-block per-row top-8.
// R11 = R10 with occupancy raised 3 -> 5 blocks/CU.
// R9/R10 post-mortem: with the XCD swizzle, staging is L2-resident
// (FETCH 68 MB) yet time is unchanged -> NOT memory-bound. R9 counters:
// MfmaUtil 16.6, VALUBusy 35.4, Occ 23% -> ~50% of cycles fully stalled
// (2-phase barrier drains) and VALU (mostly the top-8 epilogue, ~9k cyc/wave)
// out-issues MFMA 2:1. Kernel uses 88 VGPR + 32 KB LDS: 5 blocks/CU fit
// exactly (5x88=440 <= 512 VGPR/SIMD, 5x32KB = 160KB LDS). More resident
// blocks overlap one block's drain with others' MFMA/VALU (m114 mechanism).
// 128x128 tile, BK=64 (8 K-iters). Staging via global_load_lds width=16,
// unpadded row-major [128][64] bf16; XOR swizzle c_phys = c_log ^ (r&7).
__launch_bounds__(256, 5)
__global__ void score_gemm_topk_kernel(const unsigned short* __restrict__ ze16,
                                       const unsigned short* __restrict__ cb16,
                                       unsigned* __restrict__ blkTop) {
    __shared__ unsigned short Amm[128 * 64];   // 16 KB
    __shared__ unsigned short Bmm[128 * 64];   // 16 KB

    const int t    = threadIdx.x;
    const int lane = t & 63;
    const int w    = t >> 6;

    // XCD-aware bijective decode (8 XCDs, round-robin dispatch on bid&7):
    // each XCD owns 8 consecutive col-tiles (1 MB B-slice, L2-resident) and
    // sweeps row-tiles with its col-tiles innermost.
    const int bid   = blockIdx.x;              // 0..8191
    const int xcd   = bid & 7;
    const int chunk = bid >> 3;                // 0..1023
    const int cblk  = xcd * 8 + (chunk & 7);   // col-tile 0..63
    const int rblk  = chunk >> 3;              // row-tile 0..127
    const int rowBase = rblk * 128;
    const int colBase = cblk * 128;

    const int m = lane & 15;
    const int q = lane >> 4;

    floatx4 acc[2][8];
    #pragma unroll
    for (int i = 0; i < 2; ++i)
        #pragma unroll
        for (int j = 0; j < 8; ++j)
            acc[i][j] = (floatx4){0.0f, 0.0f, 0.0f, 0.0f};

    // staging: call k covers tile rows k*32 + (t>>3); phys chunk t&7 holds
    // global chunk (t&7) ^ ((t>>3)&7)
    const int tr = t >> 3;
    const int cg = (t & 7) ^ (tr & 7);
    const unsigned short* pa = ze16 + (size_t)(rowBase + tr) * DIM + cg * 8;
    const unsigned short* pb = cb16 + (size_t)(colBase + tr) * DIM + cg * 8;

    // frag chunk offsets (elements): logical chunk h*4+q, row-swizzle m&7
    const int ch0 = ((0 * 4 + q) ^ (m & 7)) * 8;
    const int ch1 = ((1 * 4 + q) ^ (m & 7)) * 8;

    for (int k0 = 0; k0 < DIM; k0 += 64) {
        __syncthreads();
        #pragma unroll
        for (int k = 0; k < 4; ++k)
            __builtin_amdgcn_global_load_lds((const GAS void*)(pa + (size_t)k * 32 * DIM + k0),
                                             (LAS void*)(Amm + (k * 256 + w * 64) * 8), 16, 0, 0);
        #pragma unroll
        for (int k = 0; k < 4; ++k)
            __builtin_amdgcn_global_load_lds((const GAS void*)(pb + (size_t)k * 32 * DIM + k0),
                                             (LAS void*)(Bmm + (k * 256 + w * 64) * 8), 16, 0, 0);
        __syncthreads();

        #pragma unroll
        for (int h = 0; h < 2; ++h) {
            const int ch = h ? ch1 : ch0;
            bhalf8 af0 = *(bhalf8*)&Amm[(w * 32 + m) * 64 + ch];
            bhalf8 af1 = *(bhalf8*)&Amm[(w * 32 + 16 + m) * 64 + ch];
            #pragma unroll
            for (int j = 0; j < 8; ++j) {
                bhalf8 bf = *(bhalf8*)&Bmm[(j * 16 + m) * 64 + ch];
                acc[0][j] = __builtin_amdgcn_mfma_f32_16x16x32_bf16(af0, bf, acc[0][j], 0, 0, 0);
                acc[1][j] = __builtin_amdgcn_mfma_f32_16x16x32_bf16(af1, bf, acc[1][j], 0, 0, 0);
            }
        }
    }

    // Epilogue (proven R7/R8). C/D layout: col = lane&15, row = quad*4 + reg.
    #pragma unroll
    for (int i = 0; i < 2; ++i) {
        #pragma unroll
        for (int reg = 0; reg < 4; ++reg) {
            const int grow = rowBase + w * 32 + i * 16 + q * 4 + reg;
            unsigned kk[8];
            #pragma unroll
            for (int j = 0; j < 8; ++j) {
                unsigned e = mkkey(-acc[i][j][reg], colBase + j * 16 + m);
                kk[j] = e;
                #pragma unroll
                for (int s = 7; s > 0; --s) {
                    if (s <= j) {
                        unsigned lo = umn(kk[s - 1], kk[s]);
                        unsigned hi = kk[s - 1] < kk[s] ? kk[s] : kk[s - 1];
                        kk[s - 1] = lo; kk[s] = hi;
                    }
                }
            }
            unsigned sval = 0;
            #pragma unroll
            for (int s = 0; s < 8; ++s) {
                unsigned g = kk[0];
                g = umn(g, (unsigned)__shfl_xor((int)g, 1, 64));
                g = umn(g, (unsigned)__shfl_xor((int)g, 2, 64));
                g = umn(g, (unsigned)__shfl_xor((int)g, 4, 64));
                g = umn(g, (unsigned)__shfl_xor((int)g, 8, 64));
                bool pop = (kk[0] == g);
                #pragma unroll
                for (int u = 0; u < 7; ++u) kk[u] = pop ? kk[u + 1] : kk[u];
                kk[7] = pop ? 0xFFFFFFFFu : kk[7];
                sval = (m == s) ? g : sval;
            }
            if (m < 8)
                blkTop[((size_t)grow * 64 + cblk) * 8 + m] = sval;
        }
    }
}

// Phase 1b: merge 64 blocks x 8 keys per row -> top-16 candidates.
__global__ void merge_topk_kernel(const unsigned* __restrict__ blkTop,
                                  int* __restrict__ cand) {
    const int wv   = threadIdx.x >> 6;
    const int lane = threadIdx.x & 63;
    const int row  = blockIdx.x * 4 + wv;
    const uint4* base = (const uint4*)(blkTop + (size_t)row * 512);

    uint4 a = base[lane * 2];
    uint4 b = base[lane * 2 + 1];
    unsigned in[8] = { a.x, a.y, a.z, a.w, b.x, b.y, b.z, b.w };
    unsigned kk[8];
    #pragma unroll
    for (int j = 0; j < 8; ++j) {
        kk[j] = in[j];
        #pragma unroll
        for (int s = 7; s > 0; --s) {
            if (s <= j) {
                unsigned lo = umn(kk[s - 1], kk[s]);
                unsigned hi = kk[s - 1] < kk[s] ? kk[s] : kk[s - 1];
                kk[s - 1] = lo; kk[s] = hi;
            }
        }
    }

    unsigned sval = 0;
    #pragma unroll
    for (int s = 0; s < NCAND; ++s) {
        unsigned g = kk[0];
        #pragma unroll
        for (int d = 32; d; d >>= 1)
            g = umn(g, (unsigned)__shfl_xor((int)g, d, 64));
        bool pop = (kk[0] == g);
        #pragma unroll
        for (int u = 0; u < 7; ++u) kk[u] = pop ? kk[u + 1] : kk[u];
        kk[7] = pop ? 0xFFFFFFFFu : kk[7];
        sval = (lane == s) ? g : sval;
    }
    if (lane < NCAND)
        cand[(size_t)row * NCAND + lane] = (int)(sval & 0xFFFFu);
}

// Phase 2: exact numpy-fp32 replica rescore (selection logic unchanged since
// R4) + FULL k_hot row write (zeros + the 4 ones in one pass; replaces the
// 512 MB memset).
__global__ void rescore_kernel(const float* __restrict__ ze,
                               const float* __restrict__ cb,
                               const int* __restrict__ cand,
                               float* __restrict__ out_zq,
                               float* __restrict__ out_khot,
                               double* __restrict__ lossAcc) {
    __shared__ float zsh[4][DIM];
    const int wv = threadIdx.x >> 6;
    const int lane = threadIdx.x & 63;
    const int row = blockIdx.x * 4 + wv;

    {
        const float* zp = ze + (size_t)row * DIM + lane * 8;
        float4 v0 = *(const float4*)zp;
        float4 v1 = *(const float4*)(zp + 4);
        *(float4*)&zsh[wv][lane * 8]     = v0;
        *(float4*)&zsh[wv][lane * 8 + 4] = v1;
    }
    __syncthreads();

    // znorm, numpy-pairwise
    float racc = 0.0f;
    {
        const int b = (lane >> 3) & 3;
        const int j = lane & 7;
        const float* zr = &zsh[wv][128 * b + j];
        #pragma unroll
        for (int i = 0; i < 16; ++i) {
            float zk = zr[8 * i];
            float sq = zk * zk;
            asm volatile("" : "+v"(sq));   // block FMA contraction into the add
            racc = racc + sq;
        }
    }
    float t1 = racc + __shfl_xor(racc, 1, 64);
    float t2 = t1 + __shfl_xor(t1, 2, 64);
    float t3 = t2 + __shfl_xor(t2, 4, 64);
    float zn = (__shfl(t3, 0, 64) + __shfl(t3, 8, 64))
             + (__shfl(t3, 16, 64) + __shfl(t3, 24, 64));

    // candidate chains: KC=384 split, sequential FMA, single accumulator each
    float qv = 3.0e38f;
    int   idxv = 0x7fffffff;
    if (lane < NCAND) {
        idxv = cand[(size_t)row * NCAND + lane];
        const float* wp = cb + (size_t)idxv * DIM;
        const float* zz = zsh[wv];
        float acc1 = 0.0f;
        for (int k = 0; k < 384; k += 8) {
            float4 wa = *(const float4*)(wp + k);
            float4 wb = *(const float4*)(wp + k + 4);
            acc1 = __builtin_fmaf(zz[k + 0], wa.x, acc1);
            acc1 = __builtin_fmaf(zz[k + 1], wa.y, acc1);
            acc1 = __builtin_fmaf(zz[k + 2], wa.z, acc1);
            acc1 = __builtin_fmaf(zz[k + 3], wa.w, acc1);
            acc1 = __builtin_fmaf(zz[k + 4], wb.x, acc1);
            acc1 = __builtin_fmaf(zz[k + 5], wb.y, acc1);
            acc1 = __builtin_fmaf(zz[k + 6], wb.z, acc1);
            acc1 = __builtin_fmaf(zz[k + 7], wb.w, acc1);
        }
        float acc2 = 0.0f;
        for (int k = 384; k < 512; k += 8) {
            float4 wa = *(const float4*)(wp + k);
            float4 wb = *(const float4*)(wp + k + 4);
            acc2 = __builtin_fmaf(zz[k + 0], wa.x, acc2);
            acc2 = __builtin_fmaf(zz[k + 1], wa.y, acc2);
            acc2 = __builtin_fmaf(zz[k + 2], wa.z, acc2);
            acc2 = __builtin_fmaf(zz[k + 3], wa.w, acc2);
            acc2 = __builtin_fmaf(zz[k + 4], wb.x, acc2);
            acc2 = __builtin_fmaf(zz[k + 5], wb.y, acc2);
            acc2 = __builtin_fmaf(zz[k + 6], wb.z, acc2);
            acc2 = __builtin_fmaf(zz[k + 7], wb.w, acc2);
        }
        float Cv = acc1 + acc2;
        qv = zn - 2.0f * Cv;
    }

    float q[NCAND]; int id[NCAND];
    #pragma unroll
    for (int c = 0; c < NCAND; ++c) {
        q[c]  = __shfl(qv, c, 64);
        id[c] = __shfl(idxv, c, 64);
    }
    int selIdx[4];
    bool used[NCAND];
    #pragma unroll
    for (int c = 0; c < NCAND; ++c) used[c] = false;
    #pragma unroll
    for (int s = 0; s < 4; ++s) {
        float bq = 3.0e38f; int bi = 0x7fffffff; int bc = -1;
        #pragma unroll
        for (int c = 0; c < NCAND; ++c) {
            bool better = !used[c] && (q[c] < bq || (q[c] == bq && id[c] < bi));
            if (better) { bq = q[c]; bi = id[c]; bc = c; }
        }
        selIdx[s] = bi;
        #pragma unroll
        for (int c = 0; c < NCAND; ++c) used[c] = used[c] || (c == bc);
    }

    float zq[8] = { 0, 0, 0, 0, 0, 0, 0, 0 };
    #pragma unroll
    for (int s = 0; s < 4; ++s) {
        const float* wp = cb + (size_t)selIdx[s] * DIM + lane * 8;
        float4 w0 = *(const float4*)wp;
        float4 w1 = *(const float4*)(wp + 4);
        zq[0] += w0.x; zq[1] += w0.y; zq[2] += w0.z; zq[3] += w0.w;
        zq[4] += w1.x; zq[5] += w1.y; zq[6] += w1.z; zq[7] += w1.w;
    }

    float zf[8];
    {
        const float* zz = &zsh[wv][lane * 8];
        #pragma unroll
        for (int i = 0; i < 8; ++i) zf[i] = zz[i];
    }
    float o[8];
    double l = 0.0;
    #pragma unroll
    for (int i = 0; i < 8; ++i) {
        float zqf  = zq[i] * 0.25f;
        float diff = zqf - zf[i];
        o[i] = zf[i] + diff;
        double ld = (double)diff;
        l += ld * ld;
    }
    {
        float* op = out_zq + (size_t)row * DIM + lane * 8;
        float4 v0 = { o[0], o[1], o[2], o[3] };
        float4 v1 = { o[4], o[5], o[6], o[7] };
        *(float4*)op = v0;
        *(float4*)(op + 4) = v1;
    }
    #pragma unroll
    for (int mm = 32; mm; mm >>= 1) l += __shfl_xor(l, mm, 64);
    if (lane == 0) atomicAdd(lossAcc, l);

    // full k_hot row write: lane owns cols {j*256 + lane*4 + e}.
    // hot mask: col -> j = col>>8, e = col&3, owner lane = (col>>2)&63.
    unsigned hotm[4] = { 0u, 0u, 0u, 0u };
    #pragma unroll
    for (int s = 0; s < 4; ++s) {
        int si = selIdx[s];
        bool own = ((si >> 2) & 63) == lane;
        int jj = si >> 8;
        unsigned bit = 1u << (((jj & 7) << 2) | (si & 3));
        int word = jj >> 3;
        #pragma unroll
        for (int wd = 0; wd < 4; ++wd)
            hotm[wd] |= (own && word == wd) ? bit : 0u;
    }
    float* kp = out_khot + (size_t)row * N_EMB;
    #pragma unroll
    for (int j = 0; j < 32; ++j) {
        unsigned bits = (hotm[j >> 3] >> ((j & 7) * 4)) & 0xFu;
        float4 v;
        v.x = (bits & 1u) ? 1.0f : 0.0f;
        v.y = (bits & 2u) ? 1.0f : 0.0f;
        v.z = (bits & 4u) ? 1.0f : 0.0f;
        v.w = (bits & 8u) ? 1.0f : 0.0f;
        *(float4*)(kp + j * 256 + lane * 4) = v;
    }
}

__global__ void finalize_kernel(const double* __restrict__ lossAcc,
                                float* __restrict__ out_loss) {
    if (threadIdx.x == 0 && blockIdx.x == 0)
        out_loss[0] = (float)(lossAcc[0] * (1.25 / ((double)N_ROWS * (double)DIM)));
}

extern "C" void kernel_launch(void* const* d_in, const int* in_sizes, int n_in,
                              void* d_out, int out_size, void* d_ws, size_t ws_size,
                              hipStream_t stream) {
    (void)in_sizes; (void)n_in; (void)out_size; (void)ws_size;
    const float* ze = (const float*)d_in[0];
    const float* cb = (const float*)d_in[1];

    float* out      = (float*)d_out;
    float* out_zq   = out;                                   // [16384, 512]
    float* out_loss = out + (size_t)N_ROWS * DIM;            // [1]
    float* out_khot = out_loss + 1;                          // [16384, 8192]

    double* lossAcc = (double*)d_ws;
    int*    cand    = (int*)((char*)d_ws + 16);

    // scratch inside k_hot region, 16B-aligned, consumed before rescore
    char* base = (char*)d_out;
    unsigned*       blkTop = (unsigned*)(base + 33554448);                  // khot + 12 B
    unsigned short* ze16   = (unsigned short*)(base + 33554448 + 33554432); // + 32 MB
    unsigned short* cb16   = ze16 + (size_t)N_ROWS * DIM;

    hipMemsetAsync(lossAcc, 0, 16, stream);

    convert_bf16_kernel<<<6144, 256, 0, stream>>>(ze, cb, ze16, cb16);
    score_gemm_topk_kernel<<<8192, 256, 0, stream>>>(ze16, cb16, blkTop);
    merge_topk_kernel<<<N_ROWS / 4, 256, 0, stream>>>(blkTop, cand);
    rescore_kernel<<<N_ROWS / 4, 256, 0, stream>>>(ze, cb, cand, out_zq, out_khot, lossAcc);
    finalize_kernel<<<1, 64, 0, stream>>>(lossAcc, out_loss);
}

// Round 4
// 998.904 us; speedup vs baseline: 1.0918x; 1.0040x over previous
//
#include <hip/hip_runtime.h>

#define N_ROWS 16384
#define N_EMB  8192
#define DIM    512
#define NCAND  16

#define GAS __attribute__((address_space(1)))
#define LAS __attribute__((address_space(3)))

// ---------------------------------------------------------------------------
// ws layout:
//   [0]    double lossAcc (16 B, zeroed)
//   [16]   int cand[N_ROWS * NCAND]   (1 MB)
// k_hot region (512 MB at d_out + 33554436 B) is scratch BEFORE rescore:
//   +12 B          : blkTop u32[N_ROWS*64*8]   (32 MB) per-block top-8 keys
//   +12+32 MB      : ze_bf16 u16[N_ROWS*DIM]   (16.8 MB)
//   then           : cb_bf16 u16[N_EMB*DIM]    ( 8.4 MB)
// Consumed by gemm/merge (stream-ordered before rescore overwrites k_hot).
// ---------------------------------------------------------------------------

typedef short  bhalf8  __attribute__((ext_vector_type(8)));
typedef float  floatx4 __attribute__((ext_vector_type(4)));

__device__ __forceinline__ unsigned short f2b(float f) {
    unsigned u = __builtin_bit_cast(unsigned, f);
    unsigned r = (u + 0x7fffu + ((u >> 16) & 1u)) >> 16;   // RNE
    return (unsigned short)r;
}
__device__ __forceinline__ unsigned pk2(float a, float b) {
    return (unsigned)f2b(a) | ((unsigned)f2b(b) << 16);
}
// sortable key: ascending u32 == ascending (score, col); lower col wins ties
__device__ __forceinline__ unsigned mkkey(float s, int col) {
    unsigned short b = f2b(s);
    unsigned short ts = (unsigned short)(b ^ ((b & 0x8000u) ? 0xFFFFu : 0x8000u));
    return ((unsigned)ts << 16) | (unsigned)col;
}
__device__ __forceinline__ unsigned umn(unsigned a, unsigned b) { return a < b ? a : b; }

// fp32 -> bf16 one-time conversion of both inputs (8 elements/thread).
__global__ void convert_bf16_kernel(const float* __restrict__ ze,
                                    const float* __restrict__ cb,
                                    unsigned short* __restrict__ ze16,
                                    unsigned short* __restrict__ cb16) {
    size_t id = (size_t)blockIdx.x * 256 + threadIdx.x;
    const size_t nze = (size_t)N_ROWS * DIM / 8;
    const float* src;
    unsigned short* dst;
    size_t off;
    if (id < nze) { src = ze; dst = ze16; off = id * 8; }
    else          { src = cb; dst = cb16; off = (id - nze) * 8; }
    float4 a = *(const float4*)(src + off);
    float4 b = *(const float4*)(src + off + 4);
    uint4 u = { pk2(a.x, a.y), pk2(a.z, a.w), pk2(b.x, b.y), pk2(b.z, b.w) };
    *(uint4*)(dst + off) = u;
}

// Phase 1a: bf16 MFMA GEMM fused with per-block per-row top-8.
// R12 = R11 GEMM core (m97 structure, 5 blk/CU, XCD swizzle) with the
// epilogue selection rewritten from {insertion-sort-8 + 8 serial
// extract-min rounds} to {Batcher sort-8 + 4 bitonic cross-lane merge
// levels}. Bitonic split: C[i] = min(A[i], B[7-i]) of two sorted-8 lists
// is bitonic and equals the bottom-8 multiset of A u B; a 12-CE clean
// re-sorts. After xor 1,2,4,8 all 16 lanes hold the identical sorted
// top-8-of-128 -> SAME BYTES into blkTop as the old extract-min loop
// (bit-identical output), at ~30% fewer ops and ~5x shorter shfl critical
// path; stores become 2x dwordx4 from one lane instead of 8x dword.
// R11 post-mortem: occupancy 3->5 blk/CU gave only +3% -> TLP saturated;
// cost model: VALU ~127us (epilogue ~95) + LDS ~130us, phase-locked.
__launch_bounds__(256, 5)
__global__ void score_gemm_topk_kernel(const unsigned short* __restrict__ ze16,
                                       const unsigned short* __restrict__ cb16,
                                       unsigned* __restrict__ blkTop) {
    __shared__ unsigned short Amm[128 * 64];   // 16 KB
    __shared__ unsigned short Bmm[128 * 64];   // 16 KB

    const int t    = threadIdx.x;
    const int lane = t & 63;
    const int w    = t >> 6;

    // XCD-aware bijective decode (8 XCDs, round-robin dispatch on bid&7):
    // each XCD owns 8 consecutive col-tiles (1 MB B-slice, L2-resident) and
    // sweeps row-tiles with its col-tiles innermost.
    const int bid   = blockIdx.x;              // 0..8191
    const int xcd   = bid & 7;
    const int chunk = bid >> 3;                // 0..1023
    const int cblk  = xcd * 8 + (chunk & 7);   // col-tile 0..63
    const int rblk  = chunk >> 3;              // row-tile 0..127
    const int rowBase = rblk * 128;
    const int colBase = cblk * 128;

    const int m = lane & 15;
    const int q = lane >> 4;

    floatx4 acc[2][8];
    #pragma unroll
    for (int i = 0; i < 2; ++i)
        #pragma unroll
        for (int j = 0; j < 8; ++j)
            acc[i][j] = (floatx4){0.0f, 0.0f, 0.0f, 0.0f};

    // staging: call k covers tile rows k*32 + (t>>3); phys chunk t&7 holds
    // global chunk (t&7) ^ ((t>>3)&7)
    const int tr = t >> 3;
    const int cg = (t & 7) ^ (tr & 7);
    const unsigned short* pa = ze16 + (size_t)(rowBase + tr) * DIM + cg * 8;
    const unsigned short* pb = cb16 + (size_t)(colBase + tr) * DIM + cg * 8;

    // frag chunk offsets (elements): logical chunk h*4+q, row-swizzle m&7
    const int ch0 = ((0 * 4 + q) ^ (m & 7)) * 8;
    const int ch1 = ((1 * 4 + q) ^ (m & 7)) * 8;

    for (int k0 = 0; k0 < DIM; k0 += 64) {
        __syncthreads();
        #pragma unroll
        for (int k = 0; k < 4; ++k)
            __builtin_amdgcn_global_load_lds((const GAS void*)(pa + (size_t)k * 32 * DIM + k0),
                                             (LAS void*)(Amm + (k * 256 + w * 64) * 8), 16, 0, 0);
        #pragma unroll
        for (int k = 0; k < 4; ++k)
            __builtin_amdgcn_global_load_lds((const GAS void*)(pb + (size_t)k * 32 * DIM + k0),
                                             (LAS void*)(Bmm + (k * 256 + w * 64) * 8), 16, 0, 0);
        __syncthreads();

        #pragma unroll
        for (int h = 0; h < 2; ++h) {
            const int ch = h ? ch1 : ch0;
            bhalf8 af0 = *(bhalf8*)&Amm[(w * 32 + m) * 64 + ch];
            bhalf8 af1 = *(bhalf8*)&Amm[(w * 32 + 16 + m) * 64 + ch];
            #pragma unroll
            for (int j = 0; j < 8; ++j) {
                bhalf8 bf = *(bhalf8*)&Bmm[(j * 16 + m) * 64 + ch];
                acc[0][j] = __builtin_amdgcn_mfma_f32_16x16x32_bf16(af0, bf, acc[0][j], 0, 0, 0);
                acc[1][j] = __builtin_amdgcn_mfma_f32_16x16x32_bf16(af1, bf, acc[1][j], 0, 0, 0);
            }
        }
    }

    // Epilogue: per (i,reg), 16-lane group holds 128 keys (8/lane); produce
    // the sorted ascending top-8 (identical multiset+order as R11's
    // extract-min loop -> bit-identical blkTop).
    // CE = compare-exchange (ascending): reads both before writes.
#define CE(x, y) { unsigned _lo = umn(kk[x], kk[y]);                         \
                   unsigned _hi = kk[x] < kk[y] ? kk[y] : kk[x];             \
                   kk[x] = _lo; kk[y] = _hi; }
    #pragma unroll
    for (int i = 0; i < 2; ++i) {
        #pragma unroll
        for (int reg = 0; reg < 4; ++reg) {
            const int grow = rowBase + w * 32 + i * 16 + q * 4 + reg;
            unsigned kk[8];
            #pragma unroll
            for (int j = 0; j < 8; ++j)
                kk[j] = mkkey(-acc[i][j][reg], colBase + j * 16 + m);

            // Batcher odd-even mergesort, 8 elements, 19 CE -> ascending
            CE(0,1) CE(2,3) CE(4,5) CE(6,7)
            CE(0,2) CE(1,3) CE(4,6) CE(5,7)
            CE(1,2) CE(5,6)
            CE(0,4) CE(1,5) CE(2,6) CE(3,7)
            CE(2,4) CE(3,5)
            CE(1,2) CE(3,4) CE(5,6)

            // 4 bitonic merge levels across lanes (xor 1,2,4,8 within the
            // 16-lane group): C[i] = min(A[i], B[7-i]) = bottom-8 multiset
            // (bitonic), then 12-CE bitonic clean -> ascending.
            #pragma unroll
            for (int d = 1; d <= 8; d <<= 1) {
                unsigned p[8];
                #pragma unroll
                for (int u = 0; u < 8; ++u)
                    p[u] = (unsigned)__shfl_xor((int)kk[u], d, 64);
                #pragma unroll
                for (int u = 0; u < 8; ++u)
                    kk[u] = umn(kk[u], p[7 - u]);
                CE(0,4) CE(1,5) CE(2,6) CE(3,7)
                CE(0,2) CE(1,3) CE(4,6) CE(5,7)
                CE(0,1) CE(2,3) CE(4,5) CE(6,7)
            }

            // all 16 lanes now hold the identical sorted top-8; one lane
            // per group stores 32 B (2x dwordx4), same bytes as before.
            if (m == 0) {
                uint4* dst = (uint4*)&blkTop[((size_t)grow * 64 + cblk) * 8];
                uint4 lo4 = { kk[0], kk[1], kk[2], kk[3] };
                uint4 hi4 = { kk[4], kk[5], kk[6], kk[7] };
                dst[0] = lo4;
                dst[1] = hi4;
            }
        }
    }
#undef CE
}

// Phase 1b: merge 64 blocks x 8 keys per row -> top-16 candidates.
__global__ void merge_topk_kernel(const unsigned* __restrict__ blkTop,
                                  int* __restrict__ cand) {
    const int wv   = threadIdx.x >> 6;
    const int lane = threadIdx.x & 63;
    const int row  = blockIdx.x * 4 + wv;
    const uint4* base = (const uint4*)(blkTop + (size_t)row * 512);

    uint4 a = base[lane * 2];
    uint4 b = base[lane * 2 + 1];
    unsigned in[8] = { a.x, a.y, a.z, a.w, b.x, b.y, b.z, b.w };
    unsigned kk[8];
    #pragma unroll
    for (int j = 0; j < 8; ++j) {
        kk[j] = in[j];
        #pragma unroll
        for (int s = 7; s > 0; --s) {
            if (s <= j) {
                unsigned lo = umn(kk[s - 1], kk[s]);
                unsigned hi = kk[s - 1] < kk[s] ? kk[s] : kk[s - 1];
                kk[s - 1] = lo; kk[s] = hi;
            }
        }
    }

    unsigned sval = 0;
    #pragma unroll
    for (int s = 0; s < NCAND; ++s) {
        unsigned g = kk[0];
        #pragma unroll
        for (int d = 32; d; d >>= 1)
            g = umn(g, (unsigned)__shfl_xor((int)g, d, 64));
        bool pop = (kk[0] == g);
        #pragma unroll
        for (int u = 0; u < 7; ++u) kk[u] = pop ? kk[u + 1] : kk[u];
        kk[7] = pop ? 0xFFFFFFFFu : kk[7];
        sval = (lane == s) ? g : sval;
    }
    if (lane < NCAND)
        cand[(size_t)row * NCAND + lane] = (int)(sval & 0xFFFFu);
}

// Phase 2: exact numpy-fp32 replica rescore (selection logic unchanged since
// R4) + FULL k_hot row write (zeros + the 4 ones in one pass; replaces the
// 512 MB memset).
__global__ void rescore_kernel(const float* __restrict__ ze,
                               const float* __restrict__ cb,
                               const int* __restrict__ cand,
                               float* __restrict__ out_zq,
                               float* __restrict__ out_khot,
                               double* __restrict__ lossAcc) {
    __shared__ float zsh[4][DIM];
    const int wv = threadIdx.x >> 6;
    const int lane = threadIdx.x & 63;
    const int row = blockIdx.x * 4 + wv;

    {
        const float* zp = ze + (size_t)row * DIM + lane * 8;
        float4 v0 = *(const float4*)zp;
        float4 v1 = *(const float4*)(zp + 4);
        *(float4*)&zsh[wv][lane * 8]     = v0;
        *(float4*)&zsh[wv][lane * 8 + 4] = v1;
    }
    __syncthreads();

    // znorm, numpy-pairwise
    float racc = 0.0f;
    {
        const int b = (lane >> 3) & 3;
        const int j = lane & 7;
        const float* zr = &zsh[wv][128 * b + j];
        #pragma unroll
        for (int i = 0; i < 16; ++i) {
            float zk = zr[8 * i];
            float sq = zk * zk;
            asm volatile("" : "+v"(sq));   // block FMA contraction into the add
            racc = racc + sq;
        }
    }
    float t1 = racc + __shfl_xor(racc, 1, 64);
    float t2 = t1 + __shfl_xor(t1, 2, 64);
    float t3 = t2 + __shfl_xor(t2, 4, 64);
    float zn = (__shfl(t3, 0, 64) + __shfl(t3, 8, 64))
             + (__shfl(t3, 16, 64) + __shfl(t3, 24, 64));

    // candidate chains: KC=384 split, sequential FMA, single accumulator each
    float qv = 3.0e38f;
    int   idxv = 0x7fffffff;
    if (lane < NCAND) {
        idxv = cand[(size_t)row * NCAND + lane];
        const float* wp = cb + (size_t)idxv * DIM;
        const float* zz = zsh[wv];
        float acc1 = 0.0f;
        for (int k = 0; k < 384; k += 8) {
            float4 wa = *(const float4*)(wp + k);
            float4 wb = *(const float4*)(wp + k + 4);
            acc1 = __builtin_fmaf(zz[k + 0], wa.x, acc1);
            acc1 = __builtin_fmaf(zz[k + 1], wa.y, acc1);
            acc1 = __builtin_fmaf(zz[k + 2], wa.z, acc1);
            acc1 = __builtin_fmaf(zz[k + 3], wa.w, acc1);
            acc1 = __builtin_fmaf(zz[k + 4], wb.x, acc1);
            acc1 = __builtin_fmaf(zz[k + 5], wb.y, acc1);
            acc1 = __builtin_fmaf(zz[k + 6], wb.z, acc1);
            acc1 = __builtin_fmaf(zz[k + 7], wb.w, acc1);
        }
        float acc2 = 0.0f;
        for (int k = 384; k < 512; k += 8) {
            float4 wa = *(const float4*)(wp + k);
            float4 wb = *(const float4*)(wp + k + 4);
            acc2 = __builtin_fmaf(zz[k + 0], wa.x, acc2);
            acc2 = __builtin_fmaf(zz[k + 1], wa.y, acc2);
            acc2 = __builtin_fmaf(zz[k + 2], wa.z, acc2);
            acc2 = __builtin_fmaf(zz[k + 3], wa.w, acc2);
            acc2 = __builtin_fmaf(zz[k + 4], wb.x, acc2);
            acc2 = __builtin_fmaf(zz[k + 5], wb.y, acc2);
            acc2 = __builtin_fmaf(zz[k + 6], wb.z, acc2);
            acc2 = __builtin_fmaf(zz[k + 7], wb.w, acc2);
        }
        float Cv = acc1 + acc2;
        qv = zn - 2.0f * Cv;
    }

    float q[NCAND]; int id[NCAND];
    #pragma unroll
    for (int c = 0; c < NCAND; ++c) {
        q[c]  = __shfl(qv, c, 64);
        id[c] = __shfl(idxv, c, 64);
    }
    int selIdx[4];
    bool used[NCAND];
    #pragma unroll
    for (int c = 0; c < NCAND; ++c) used[c] = false;
    #pragma unroll
    for (int s = 0; s < 4; ++s) {
        float bq = 3.0e38f; int bi = 0x7fffffff; int bc = -1;
        #pragma unroll
        for (int c = 0; c < NCAND; ++c) {
            bool better = !used[c] && (q[c] < bq || (q[c] == bq && id[c] < bi));
            if (better) { bq = q[c]; bi = id[c]; bc = c; }
        }
        selIdx[s] = bi;
        #pragma unroll
        for (int c = 0; c < NCAND; ++c) used[c] = used[c] || (c == bc);
    }

    float zq[8] = { 0, 0, 0, 0, 0, 0, 0, 0 };
    #pragma unroll
    for (int s = 0; s < 4; ++s) {
        const float* wp = cb + (size_t)selIdx[s] * DIM + lane * 8;
        float4 w0 = *(const float4*)wp;
        float4 w1 = *(const float4*)(wp + 4);
        zq[0] += w0.x; zq[1] += w0.y; zq[2] += w0.z; zq[3] += w0.w;
        zq[4] += w1.x; zq[5] += w1.y; zq[6] += w1.z; zq[7] += w1.w;
    }

    float zf[8];
    {
        const float* zz = &zsh[wv][lane * 8];
        #pragma unroll
        for (int i = 0; i < 8; ++i) zf[i] = zz[i];
    }
    float o[8];
    double l = 0.0;
    #pragma unroll
    for (int i = 0; i < 8; ++i) {
        float zqf  = zq[i] * 0.25f;
        float diff = zqf - zf[i];
        o[i] = zf[i] + diff;
        double ld = (double)diff;
        l += ld * ld;
    }
    {
        float* op = out_zq + (size_t)row * DIM + lane * 8;
        float4 v0 = { o[0], o[1], o[2], o[3] };
        float4 v1 = { o[4], o[5], o[6], o[7] };
        *(float4*)op = v0;
        *(float4*)(op + 4) = v1;
    }
    #pragma unroll
    for (int mm = 32; mm; mm >>= 1) l += __shfl_xor(l, mm, 64);
    if (lane == 0) atomicAdd(lossAcc, l);

    // full k_hot row write: lane owns cols {j*256 + lane*4 + e}.
    // hot mask: col -> j = col>>8, e = col&3, owner lane = (col>>2)&63.
    unsigned hotm[4] = { 0u, 0u, 0u, 0u };
    #pragma unroll
    for (int s = 0; s < 4; ++s) {
        int si = selIdx[s];
        bool own = ((si >> 2) & 63) == lane;
        int jj = si >> 8;
        unsigned bit = 1u << (((jj & 7) << 2) | (si & 3));
        int word = jj >> 3;
        #pragma unroll
        for (int wd = 0; wd < 4; ++wd)
            hotm[wd] |= (own && word == wd) ? bit : 0u;
    }
    float* kp = out_khot + (size_t)row * N_EMB;
    #pragma unroll
    for (int j = 0; j < 32; ++j) {
        unsigned bits = (hotm[j >> 3] >> ((j & 7) * 4)) & 0xFu;
        float4 v;
        v.x = (bits & 1u) ? 1.0f : 0.0f;
        v.y = (bits & 2u) ? 1.0f : 0.0f;
        v.z = (bits & 4u) ? 1.0f : 0.0f;
        v.w = (bits & 8u) ? 1.0f : 0.0f;
        *(float4*)(kp + j * 256 + lane * 4) = v;
    }
}

__global__ void finalize_kernel(const double* __restrict__ lossAcc,
                                float* __restrict__ out_loss) {
    if (threadIdx.x == 0 && blockIdx.x == 0)
        out_loss[0] = (float)(lossAcc[0] * (1.25 / ((double)N_ROWS * (double)DIM)));
}

extern "C" void kernel_launch(void* const* d_in, const int* in_sizes, int n_in,
                              void* d_out, int out_size, void* d_ws, size_t ws_size,
                              hipStream_t stream) {
    (void)in_sizes; (void)n_in; (void)out_size; (void)ws_size;
    const float* ze = (const float*)d_in[0];
    const float* cb = (const float*)d_in[1];

    float* out      = (float*)d_out;
    float* out_zq   = out;                                   // [16384, 512]
    float* out_loss = out + (size_t)N_ROWS * DIM;            // [1]
    float* out_khot = out_loss + 1;                          // [16384, 8192]

    double* lossAcc = (double*)d_ws;
    int*    cand    = (int*)((char*)d_ws + 16);

    // scratch inside k_hot region, 16B-aligned, consumed before rescore
    char* base = (char*)d_out;
    unsigned*       blkTop = (unsigned*)(base + 33554448);                  // khot + 12 B
    unsigned short* ze16   = (unsigned short*)(base + 33554448 + 33554432); // + 32 MB
    unsigned short* cb16   = ze16 + (size_t)N_ROWS * DIM;

    hipMemsetAsync(lossAcc, 0, 16, stream);

    convert_bf16_kernel<<<6144, 256, 0, stream>>>(ze, cb, ze16, cb16);
    score_gemm_topk_kernel<<<8192, 256, 0, stream>>>(ze16, cb16, blkTop);
    merge_topk_kernel<<<N_ROWS / 4, 256, 0, stream>>>(blkTop, cand);
    rescore_kernel<<<N_ROWS / 4, 256, 0, stream>>>(ze, cb, cand, out_zq, out_khot, lossAcc);
    finalize_kernel<<<1, 64, 0, stream>>>(lossAcc, out_loss);
}